// Round 3
// baseline (195.676 us; speedup 1.0000x reference)
//
#include <hip/hip_runtime.h>

typedef __attribute__((ext_vector_type(8))) short bf16x8;
typedef __attribute__((ext_vector_type(4))) float f32x4;
typedef __attribute__((ext_vector_type(8))) unsigned short u16x8;

constexpr int Bn = 16;
constexpr int Nn = 512;
constexpr int Fn = 64;
constexpr int Aout = 512;

static __device__ __forceinline__ unsigned short f2bf(float f) {
  union { float f; unsigned int u; } v; v.f = f;
  unsigned int r = v.u + 0x7fffu + ((v.u >> 16) & 1u);
  return (unsigned short)(r >> 16);
}
static __device__ __forceinline__ float bf2f(unsigned short u) {
  union { unsigned int u; float f; } v; v.u = ((unsigned int)u) << 16;
  return v.f;
}

// ---------------------------------------------------------------------------
// adjs0/1/2 fp32 -> bf16 x3 + bf16 sum. one float4 per thread.
// ---------------------------------------------------------------------------
__launch_bounds__(256)
__global__ void conv3_kernel(const float4* __restrict__ a0,
                             const float4* __restrict__ a1,
                             const float4* __restrict__ a2,
                             ushort4* __restrict__ o0,
                             ushort4* __restrict__ o1,
                             ushort4* __restrict__ o2,
                             ushort4* __restrict__ os) {
  size_t i = (size_t)blockIdx.x * 256 + threadIdx.x;
  float4 x = a0[i], y = a1[i], z = a2[i];
  ushort4 p;
  p.x = f2bf(x.x); p.y = f2bf(x.y); p.z = f2bf(x.z); p.w = f2bf(x.w);
  o0[i] = p;
  p.x = f2bf(y.x); p.y = f2bf(y.y); p.z = f2bf(y.z); p.w = f2bf(y.w);
  o1[i] = p;
  p.x = f2bf(z.x); p.y = f2bf(z.y); p.z = f2bf(z.z); p.w = f2bf(z.w);
  o2[i] = p;
  p.x = f2bf(x.x + y.x + z.x); p.y = f2bf(x.y + y.y + z.y);
  p.z = f2bf(x.z + y.z + z.z); p.w = f2bf(x.w + y.w + z.w);
  os[i] = p;
}

__launch_bounds__(256)
__global__ void convb_kernel(const float4* __restrict__ a,
                             ushort4* __restrict__ o) {
  size_t i = (size_t)blockIdx.x * 256 + threadIdx.x;
  float4 x = a[i];
  ushort4 p;
  p.x = f2bf(x.x); p.y = f2bf(x.y); p.z = f2bf(x.z); p.w = f2bf(x.w);
  o[i] = p;
}

// W_init [512][64] fp32 -> W_initT [64][512] bf16
__launch_bounds__(256)
__global__ void convWT_kernel(const float* __restrict__ W,
                              unsigned short* __restrict__ WT) {
  int o = blockIdx.x * 256 + threadIdx.x;  // 32768
  int f = o >> 9, k = o & 511;
  WT[o] = f2bf(W[k * Fn + f]);
}

// ---------------------------------------------------------------------------
// Pipelined MFMA GEMM: outT[z][b] (64F x 512N, bf16) = sum_seg A_seg @ X_seg.
// A: [512][512] bf16 row-major. X transposed [64][512]. 128 thr = 2 waves,
// block tile 32 rows x 64 cols, K-step 64, double-buffered LDS (padded rows),
// 2-phase reg-staged pipeline (issue next tile's loads before barrier).
// ---------------------------------------------------------------------------
struct MArgs {
  const unsigned short* A0[3];
  const unsigned short* A1[3];
  const unsigned short* X0[3];
  const unsigned short* X1[3];
  unsigned short* O[3];
  long long x0_bs, x1_bs;  // X batch strides (elements)
  int nt;                  // K tiles of 64: 8 per segment
  const float* mean; const float* var; const float* gamma; const float* beta;
};

__launch_bounds__(128, 2)
__global__ void gemm_T_kernel(MArgs args) {
  const int z = blockIdx.z, b = blockIdx.y;
  const int R00 = blockIdx.x * 32;
  const int tid = threadIdx.x;
  const int w = tid >> 6, l = tid & 63;
  const int lr = l & 15, q = l >> 4;

  __shared__ unsigned short As[2][32][72];  // 32 rows x 64 k, row pad to 72
  __shared__ unsigned short Xs[2][64][72];  // 64 cols x 64 k

  // per-thread staging offsets (elements)
  int aoff[2], xoff[4], awr[2], awk[2], xwr[4], xwk[4];
#pragma unroll
  for (int j = 0; j < 2; ++j) {
    int c = tid + 128 * j;
    awr[j] = c >> 3; awk[j] = (c & 7) * 8;
    aoff[j] = awr[j] * 512 + awk[j];
  }
#pragma unroll
  for (int j = 0; j < 4; ++j) {
    int c = tid + 128 * j;
    xwr[j] = c >> 3; xwk[j] = (c & 7) * 8;
    xoff[j] = xwr[j] * 512 + xwk[j];
  }

  const unsigned short* Ab0 = args.A0[z] + ((size_t)b << 18) + (size_t)R00 * 512;
  const unsigned short* Xb0 = args.X0[z] + (size_t)b * args.x0_bs;
  const unsigned short* Ab1 =
      args.A1[z] ? args.A1[z] + ((size_t)b << 18) + (size_t)R00 * 512 : Ab0;
  const unsigned short* Xb1 =
      args.X1[z] ? args.X1[z] + (size_t)b * args.x1_bs : Xb0;

  f32x4 acc0 = {0.f, 0.f, 0.f, 0.f};
  f32x4 acc1 = acc0, acc2 = acc0, acc3 = acc0;

  uint4 ra[6], rb[6];  // [0:2) = A chunks, [2:6) = X chunks

#define ISSUE(R, T)                                                          \
  {                                                                          \
    const unsigned short* Ab_ = ((T) < 8) ? Ab0 : Ab1;                       \
    const unsigned short* Xb_ = ((T) < 8) ? Xb0 : Xb1;                       \
    const int k0_ = ((T)&7) * 64;                                            \
    _Pragma("unroll") for (int j = 0; j < 2; ++j)                            \
        R[j] = *(const uint4*)(Ab_ + k0_ + aoff[j]);                         \
    _Pragma("unroll") for (int j = 0; j < 4; ++j)                            \
        R[2 + j] = *(const uint4*)(Xb_ + k0_ + xoff[j]);                     \
  }

#define WRITE(R, BUF)                                                        \
  {                                                                          \
    _Pragma("unroll") for (int j = 0; j < 2; ++j)                            \
        *(uint4*)&As[BUF][awr[j]][awk[j]] = R[j];                            \
    _Pragma("unroll") for (int j = 0; j < 4; ++j)                            \
        *(uint4*)&Xs[BUF][xwr[j]][xwk[j]] = R[2 + j];                        \
  }

#define COMPUTE(BUF)                                                         \
  {                                                                          \
    _Pragma("unroll") for (int h = 0; h < 2; ++h) {                          \
      bf16x8 af = *(const bf16x8*)&As[BUF][w * 16 + lr][h * 32 + q * 8];     \
      bf16x8 x0 = *(const bf16x8*)&Xs[BUF][lr][h * 32 + q * 8];              \
      bf16x8 x1 = *(const bf16x8*)&Xs[BUF][16 + lr][h * 32 + q * 8];         \
      bf16x8 x2 = *(const bf16x8*)&Xs[BUF][32 + lr][h * 32 + q * 8];         \
      bf16x8 x3 = *(const bf16x8*)&Xs[BUF][48 + lr][h * 32 + q * 8];         \
      acc0 = __builtin_amdgcn_mfma_f32_16x16x32_bf16(af, x0, acc0, 0, 0, 0); \
      acc1 = __builtin_amdgcn_mfma_f32_16x16x32_bf16(af, x1, acc1, 0, 0, 0); \
      acc2 = __builtin_amdgcn_mfma_f32_16x16x32_bf16(af, x2, acc2, 0, 0, 0); \
      acc3 = __builtin_amdgcn_mfma_f32_16x16x32_bf16(af, x3, acc3, 0, 0, 0); \
    }                                                                        \
  }

  const int nt = args.nt;  // always even (8 or 16)
  ISSUE(ra, 0);
  for (int t = 0; t < nt; t += 2) {
    WRITE(ra, 0);
    ISSUE(rb, t + 1);
    __syncthreads();
    COMPUTE(0);
    WRITE(rb, 1);
    if (t + 2 < nt) ISSUE(ra, t + 2);
    __syncthreads();
    COMPUTE(1);
  }
#undef ISSUE
#undef WRITE
#undef COMPUTE

  unsigned short* Ob = args.O[z] + ((size_t)b << 15);
  const int rbase = R00 + w * 16 + q * 4;  // 4 consecutive output rows
  float sc[4], mu[4], bt[4];
  const bool hasbn = args.mean != nullptr;
  if (hasbn) {
#pragma unroll
    for (int i = 0; i < 4; ++i) {
      int n = rbase + i;
      sc[i] = rsqrtf(args.var[n] + 1e-5f) * args.gamma[n];
      mu[i] = args.mean[n];
      bt[i] = args.beta[n];
    }
  }
  f32x4 accs[4] = {acc0, acc1, acc2, acc3};
#pragma unroll
  for (int c = 0; c < 4; ++c) {
    int col = c * 16 + lr;
    ushort4 wv;
#pragma unroll
    for (int i = 0; i < 4; ++i) {
      float v = accs[c][i];
      if (hasbn) v = fmaxf(fmaf(v - mu[i], sc[i], bt[i]), 0.f);
      ((unsigned short*)&wv)[i] = f2bf(v);
    }
    *(ushort4*)(Ob + ((size_t)col << 9) + rbase) = wv;
  }
}

// ---------------------------------------------------------------------------
// h_nextT = bf16( relu(BN_l( h@W3 + b + P0@W0 + P1@W1 + P2@W2 )) ), all
// inputs transposed bf16 [64][512] per b. Block: (b, 16 n-cols), 256 thr.
// ---------------------------------------------------------------------------
__launch_bounds__(256)
__global__ void fuse_T_kernel(const unsigned short* __restrict__ hT,
                              const unsigned short* __restrict__ P0T,
                              const unsigned short* __restrict__ P1T,
                              const unsigned short* __restrict__ P2T,
                              const float* __restrict__ W3,
                              const float* __restrict__ W0,
                              const float* __restrict__ W1,
                              const float* __restrict__ W2,
                              const float* __restrict__ bias,
                              const float* __restrict__ mean,
                              const float* __restrict__ var,
                              const float* __restrict__ gamma,
                              const float* __restrict__ beta,
                              unsigned short* __restrict__ outT) {
  const int b = blockIdx.y;
  const int n0 = blockIdx.x * 16;
  const int t = threadIdx.x;
  __shared__ __align__(16) unsigned short lds[4][64][16];
  {
    const int mat = t >> 6, k = t & 63;
    const unsigned short* srcs[4] = {hT, P0T, P1T, P2T};
    const unsigned short* s = srcs[mat] + ((size_t)b << 15) + ((size_t)k << 9) + n0;
    *(uint4*)&lds[mat][k][0] = *(const uint4*)s;
    *(uint4*)&lds[mat][k][8] = *(const uint4*)(s + 8);
  }
  __syncthreads();
  const int fo = t & 63, g = t >> 6;
  float acc[4];
#pragma unroll
  for (int i = 0; i < 4; ++i) acc[i] = bias[fo];
  const float* Ws[4] = {W3, W0, W1, W2};
  for (int mat = 0; mat < 4; ++mat) {
    const float* __restrict__ W = Ws[mat];
#pragma unroll 8
    for (int k = 0; k < 64; ++k) {
      float wv = W[k * 64 + fo];
#pragma unroll
      for (int i = 0; i < 4; ++i)
        acc[i] = fmaf(bf2f(lds[mat][k][g * 4 + i]), wv, acc[i]);
    }
  }
  ushort4 o;
#pragma unroll
  for (int i = 0; i < 4; ++i) {
    int n = n0 + g * 4 + i;
    float sc = rsqrtf(var[n] + 1e-5f) * gamma[n];
    float v = fmaf(acc[i] - mean[n], sc, beta[n]);
    ((unsigned short*)&o)[i] = f2bf(fmaxf(v, 0.f));
  }
  *(ushort4*)(outT + ((size_t)b << 15) + ((size_t)fo << 9) + n0 + g * 4) = o;
}

// ---------------------------------------------------------------------------
// head: sum over n (contiguous in h3T), BN+ReLU, FC 512, softmax. block per b.
// ---------------------------------------------------------------------------
__launch_bounds__(256)
__global__ void head_T_kernel(const unsigned short* __restrict__ h3T,
                              const float* __restrict__ gmean,
                              const float* __restrict__ gvar,
                              const float* __restrict__ ggamma,
                              const float* __restrict__ gbeta,
                              const float* __restrict__ fc_w,
                              const float* __restrict__ fc_b,
                              float* __restrict__ out) {
  const int b = blockIdx.x;
  const int t = threadIdx.x;
  __shared__ float part[256];
  __shared__ float gh[64];
  __shared__ float red[256];

  const int f = t >> 2, q = t & 3;
  const unsigned short* hp = h3T + ((size_t)b << 15) + ((size_t)f << 9) + q * 128;
  float s = 0.f;
#pragma unroll
  for (int j = 0; j < 16; ++j) {
    u16x8 v = *(const u16x8*)(hp + j * 8);
#pragma unroll
    for (int e = 0; e < 8; ++e) s += bf2f((unsigned short)v[e]);
  }
  part[t] = s;
  __syncthreads();
  if (t < 64) {
    float sum = part[t * 4] + part[t * 4 + 1] + part[t * 4 + 2] + part[t * 4 + 3];
    float sc = rsqrtf(gvar[t] + 1e-5f) * ggamma[t];
    float v = fmaf(sum - gmean[t], sc, gbeta[t]);
    gh[t] = v > 0.f ? v : 0.f;
  }
  __syncthreads();

  float lg[2];
#pragma unroll
  for (int rep = 0; rep < 2; ++rep) {
    const int a = t + rep * 256;
    const float* __restrict__ wv = fc_w + (size_t)a * Fn;
    float acc = fc_b[a];
#pragma unroll 8
    for (int kk = 0; kk < 64; ++kk) acc = fmaf(gh[kk], wv[kk], acc);
    lg[rep] = acc;
  }
  red[t] = fmaxf(lg[0], lg[1]);
  __syncthreads();
  for (int off = 128; off > 0; off >>= 1) {
    if (t < off) red[t] = fmaxf(red[t], red[t + off]);
    __syncthreads();
  }
  const float mx = red[0];
  __syncthreads();
  const float e0 = __expf(lg[0] - mx), e1 = __expf(lg[1] - mx);
  red[t] = e0 + e1;
  __syncthreads();
  for (int off = 128; off > 0; off >>= 1) {
    if (t < off) red[t] += red[t + off];
    __syncthreads();
  }
  const float inv = 1.f / red[0];
  out[(size_t)b * Aout + t] = e0 * inv;
  out[(size_t)b * Aout + t + 256] = e1 * inv;
}

// ---------------------------------------------------------------------------
extern "C" void kernel_launch(void* const* d_in, const int* in_sizes, int n_in,
                              void* d_out, int out_size, void* d_ws,
                              size_t ws_size, hipStream_t stream) {
  (void)in_sizes; (void)n_in; (void)out_size; (void)ws_size;
  const float* hs_init = (const float*)d_in[0];
  const float* adjs0 = (const float*)d_in[1];
  const float* adjs1 = (const float*)d_in[2];
  const float* adjs2 = (const float*)d_in[3];
  const float* W_init = (const float*)d_in[4];
  const float* W0 = (const float*)d_in[5];
  const float* W1 = (const float*)d_in[6];
  const float* W2 = (const float*)d_in[7];
  const float* W3 = (const float*)d_in[8];
  const float* bvec = (const float*)d_in[9];
  const float* fc1_w = (const float*)d_in[10];
  const float* fc1_b = (const float*)d_in[11];
  const float* bn_init_mean = (const float*)d_in[12];
  const float* bn_init_var = (const float*)d_in[13];
  const float* bn_init_gamma = (const float*)d_in[14];
  const float* bn_init_beta = (const float*)d_in[15];
  const float* bn_layer_mean = (const float*)d_in[16];
  const float* bn_layer_var = (const float*)d_in[17];
  const float* bn_layer_gamma = (const float*)d_in[18];
  const float* bn_layer_beta = (const float*)d_in[19];
  const float* bn_graph_mean = (const float*)d_in[20];
  const float* bn_graph_var = (const float*)d_in[21];
  const float* bn_graph_gamma = (const float*)d_in[22];
  const float* bn_graph_beta = (const float*)d_in[23];

  const size_t ADJ = (size_t)Bn * Nn * Nn;  // 4,194,304 elems
  const size_t NF = (size_t)Bn * Fn * Nn;   // 524,288 elems

  unsigned short* W = (unsigned short*)d_ws;
  unsigned short* adjsb = W;             // bf16 sum
  unsigned short* a0b = W + ADJ;
  unsigned short* a1b = W + 2 * ADJ;
  unsigned short* a2b = W + 3 * ADJ;
  unsigned short* WiT = W + 4 * ADJ;     // 32768
  unsigned short* h0T = WiT + 32768;
  unsigned short* h3T = h0T;             // alias: h0T dead before fuse3 writes
  unsigned short* h1T = h0T + NF;
  unsigned short* h2T = h1T + NF;
  unsigned short* Pa0 = h2T + NF;
  unsigned short* Pa1 = Pa0 + NF;
  unsigned short* Pa2 = Pa1 + NF;
  unsigned short* Pb0 = Pa2 + NF;
  unsigned short* Pb1 = Pb0 + NF;
  unsigned short* Pb2 = Pb1 + NF;
  unsigned short* hsb = h1T;             // alias: spans 8*NF, all written later

  conv3_kernel<<<dim3((unsigned)(ADJ / 4 / 256)), dim3(256), 0, stream>>>(
      (const float4*)adjs0, (const float4*)adjs1, (const float4*)adjs2,
      (ushort4*)a0b, (ushort4*)a1b, (ushort4*)a2b, (ushort4*)adjsb);
  convb_kernel<<<dim3((unsigned)(ADJ / 4 / 256)), dim3(256), 0, stream>>>(
      (const float4*)hs_init, (ushort4*)hsb);
  convWT_kernel<<<dim3(128), dim3(256), 0, stream>>>(W_init, WiT);

  const long long nfb = (long long)Fn * Nn;  // 32768

  // h0 = relu(BN_init(hs_init @ W_init))   (outputs h0T)
  {
    MArgs a = {};
    a.A0[0] = hsb; a.X0[0] = WiT; a.O[0] = h0T;
    a.x0_bs = 0; a.nt = 8;
    a.mean = bn_init_mean; a.var = bn_init_var;
    a.gamma = bn_init_gamma; a.beta = bn_init_beta;
    gemm_T_kernel<<<dim3(16, Bn, 1), dim3(128), 0, stream>>>(a);
  }

  const unsigned short* akb[3] = {a0b, a1b, a2b};

  // layer 0: Pa_k = adjs_k @ h0
  {
    MArgs a = {};
    unsigned short* O[3] = {Pa0, Pa1, Pa2};
    for (int k = 0; k < 3; ++k) { a.A0[k] = akb[k]; a.X0[k] = h0T; a.O[k] = O[k]; }
    a.x0_bs = nfb; a.nt = 8;
    gemm_T_kernel<<<dim3(16, Bn, 3), dim3(128), 0, stream>>>(a);
  }
  fuse_T_kernel<<<dim3(32, Bn), dim3(256), 0, stream>>>(
      h0T, Pa0, Pa1, Pa2, W3, W0, W1, W2, bvec, bn_layer_mean, bn_layer_var,
      bn_layer_gamma, bn_layer_beta, h1T);

  // layer 1: Pb_k = adjs_k @ h1 + adjs @ Pa_k   (fused K=1024)
  {
    MArgs a = {};
    unsigned short* O[3] = {Pb0, Pb1, Pb2};
    const unsigned short* Xs2[3] = {Pa0, Pa1, Pa2};
    for (int k = 0; k < 3; ++k) {
      a.A0[k] = akb[k]; a.X0[k] = h1T;
      a.A1[k] = adjsb; a.X1[k] = Xs2[k]; a.O[k] = O[k];
    }
    a.x0_bs = nfb; a.x1_bs = nfb; a.nt = 16;
    gemm_T_kernel<<<dim3(16, Bn, 3), dim3(128), 0, stream>>>(a);
  }
  fuse_T_kernel<<<dim3(32, Bn), dim3(256), 0, stream>>>(
      h1T, Pb0, Pb1, Pb2, W3 + Fn * Fn, W0 + Fn * Fn, W1 + Fn * Fn,
      W2 + Fn * Fn, bvec + Fn, bn_layer_mean + Nn, bn_layer_var + Nn,
      bn_layer_gamma + Nn, bn_layer_beta + Nn, h2T);

  // layer 2: Pa_k = adjs_k @ h2 + adjs @ Pb_k
  {
    MArgs a = {};
    unsigned short* O[3] = {Pa0, Pa1, Pa2};
    const unsigned short* Xs2[3] = {Pb0, Pb1, Pb2};
    for (int k = 0; k < 3; ++k) {
      a.A0[k] = akb[k]; a.X0[k] = h2T;
      a.A1[k] = adjsb; a.X1[k] = Xs2[k]; a.O[k] = O[k];
    }
    a.x0_bs = nfb; a.x1_bs = nfb; a.nt = 16;
    gemm_T_kernel<<<dim3(16, Bn, 3), dim3(128), 0, stream>>>(a);
  }
  fuse_T_kernel<<<dim3(32, Bn), dim3(256), 0, stream>>>(
      h2T, Pa0, Pa1, Pa2, W3 + 2 * Fn * Fn, W0 + 2 * Fn * Fn,
      W1 + 2 * Fn * Fn, W2 + 2 * Fn * Fn, bvec + 2 * Fn,
      bn_layer_mean + 2 * Nn, bn_layer_var + 2 * Nn, bn_layer_gamma + 2 * Nn,
      bn_layer_beta + 2 * Nn, h3T);

  head_T_kernel<<<dim3(Bn), dim3(256), 0, stream>>>(
      h3T, bn_graph_mean, bn_graph_var, bn_graph_gamma, bn_graph_beta, fc1_w,
      fc1_b, (float*)d_out);
}

// Round 4
// 190.488 us; speedup vs baseline: 1.0272x; 1.0272x over previous
//
#include <hip/hip_runtime.h>

typedef __attribute__((ext_vector_type(8))) short bf16x8;
typedef __attribute__((ext_vector_type(4))) float f32x4;
typedef __attribute__((ext_vector_type(8))) unsigned short u16x8;

constexpr int Bn = 16;
constexpr int Nn = 512;
constexpr int Fn = 64;
constexpr int Aout = 512;

static __device__ __forceinline__ unsigned short f2bf(float f) {
  union { float f; unsigned int u; } v; v.f = f;
  unsigned int r = v.u + 0x7fffu + ((v.u >> 16) & 1u);
  return (unsigned short)(r >> 16);
}
static __device__ __forceinline__ float bf2f(unsigned short u) {
  union { unsigned int u; float f; } v; v.u = ((unsigned int)u) << 16;
  return v.f;
}
// pack two fp32 -> two bf16 (round-half-up; inputs finite)
static __device__ __forceinline__ unsigned int pk2(float a, float b) {
  union { float f; unsigned int u; } ua, ub; ua.f = a; ub.f = b;
  return ((ua.u + 0x8000u) >> 16) | ((ub.u + 0x8000u) & 0xFFFF0000u);
}

// ---------------------------------------------------------------------------
// prep: adjs_sum -> bf16 (blocks < 4096), W_init -> W_init^T bf16 (last 128)
// ---------------------------------------------------------------------------
__launch_bounds__(256)
__global__ void prep_kernel(const float4* __restrict__ a0,
                            const float4* __restrict__ a1,
                            const float4* __restrict__ a2,
                            ushort4* __restrict__ osum,
                            const float* __restrict__ Wi,
                            unsigned short* __restrict__ WiT) {
  const int blk = blockIdx.x;
  if (blk < 4096) {
    size_t i = (size_t)blk * 256 + threadIdx.x;
    float4 x = a0[i], y = a1[i], z = a2[i];
    ushort4 p;
    p.x = f2bf(x.x + y.x + z.x);
    p.y = f2bf(x.y + y.y + z.y);
    p.z = f2bf(x.z + y.z + z.z);
    p.w = f2bf(x.w + y.w + z.w);
    osum[i] = p;
  } else {
    int o = (blk - 4096) * 256 + threadIdx.x;  // 32768 = 64f x 512k
    int f = o >> 9, k = o & 511;
    WiT[o] = f2bf(Wi[k * Fn + f]);
  }
}

// ---------------------------------------------------------------------------
// Split-K MFMA GEMM. Block: 64 A-rows x 64 f x nz z's; K-split 256.
// A seg0: fp32 (per-z), A seg1: bf16 shared (adjs sum). X: bf16 [64][512]/b.
// A/B frags straight global->reg (no input LDS). Output partial bf16
// [z][s][b][f][n] routed through LDS transpose for contiguous 128B rows.
// ---------------------------------------------------------------------------
struct GArgs {
  const float* A0f[3];
  const unsigned short* A1;
  const unsigned short* X0[3];
  const unsigned short* X1[3];
  unsigned short* O;
  long long x0_bs;
  int nz, ns0, ns;
};

__launch_bounds__(256, 2)
__global__ void gemm_split_kernel(GArgs g) {
  const int b = blockIdx.y;
  const int s = blockIdx.z;
  const int R0 = blockIdx.x * 64;
  const int tid = threadIdx.x;
  const int w = tid >> 6, l = tid & 63;
  const int lr = l & 15, q = l >> 4;
  const int seg = (s >= g.ns0) ? 1 : 0;
  const int kbase = (seg ? (s - g.ns0) : s) * 256;
  const int arow = R0 + w * 16 + lr;
  const size_t aoff = ((size_t)b << 18) + ((size_t)arow << 9) + kbase + q * 8;

  __shared__ __align__(16) unsigned short outLDS[64][72];

  bf16x8 af[8];
  if (seg) {  // bf16 shared A: load once, reuse across z
    const unsigned short* A = g.A1 + aoff;
#pragma unroll
    for (int k = 0; k < 8; ++k) af[k] = *(const bf16x8*)(A + k * 32);
  }

  for (int z = 0; z < g.nz; ++z) {
    if (!seg) {  // fp32 per-z A: load + pack to bf16
      const float* A = g.A0f[z] + aoff;
#pragma unroll
      for (int k = 0; k < 8; ++k) {
        float4 lo = *(const float4*)(A + k * 32);
        float4 hi = *(const float4*)(A + k * 32 + 4);
        union { bf16x8 v; unsigned int u[4]; } cv;
        cv.u[0] = pk2(lo.x, lo.y);
        cv.u[1] = pk2(lo.z, lo.w);
        cv.u[2] = pk2(hi.x, hi.y);
        cv.u[3] = pk2(hi.z, hi.w);
        af[k] = cv.v;
      }
    }
    const unsigned short* X = seg ? (g.X1[z] + ((size_t)b << 15))
                                  : (g.X0[z] + (size_t)b * g.x0_bs);
    const unsigned short* Xp = X + ((size_t)lr << 9) + kbase + q * 8;

    f32x4 acc[4] = {{0.f, 0.f, 0.f, 0.f},
                    {0.f, 0.f, 0.f, 0.f},
                    {0.f, 0.f, 0.f, 0.f},
                    {0.f, 0.f, 0.f, 0.f}};
    bf16x8 xc[4], xn[4];
#pragma unroll
    for (int c = 0; c < 4; ++c) xc[c] = *(const bf16x8*)(Xp + c * 8192);
#pragma unroll
    for (int k = 0; k < 8; ++k) {
      if (k < 7) {
#pragma unroll
        for (int c = 0; c < 4; ++c)
          xn[c] = *(const bf16x8*)(Xp + c * 8192 + (k + 1) * 32);
      }
#pragma unroll
      for (int c = 0; c < 4; ++c)
        acc[c] = __builtin_amdgcn_mfma_f32_16x16x32_bf16(af[k], xc[c], acc[c], 0, 0, 0);
      if (k < 7) {
#pragma unroll
        for (int c = 0; c < 4; ++c) xc[c] = xn[c];
      }
    }

    // epilogue: LDS transpose so global stores are contiguous per f-row
    __syncthreads();
#pragma unroll
    for (int c = 0; c < 4; ++c) {
      ushort4 wv;
#pragma unroll
      for (int i = 0; i < 4; ++i) ((unsigned short*)&wv)[i] = f2bf(acc[c][i]);
      *(ushort4*)&outLDS[c * 16 + lr][w * 16 + q * 4] = wv;
    }
    __syncthreads();
    {
      const int fr = tid >> 2, c4 = tid & 3;
      unsigned short* O = g.O + ((((size_t)z * g.ns + s) * 16 + b) << 15) +
                          ((size_t)fr << 9) + R0 + c4 * 16;
      u16x8 v0 = *(const u16x8*)&outLDS[fr][c4 * 16];
      u16x8 v1 = *(const u16x8*)&outLDS[fr][c4 * 16 + 8];
      *(u16x8*)O = v0;
      *(u16x8*)(O + 8) = v1;
    }
  }
}

// ---------------------------------------------------------------------------
// h0 epilogue: sum 2 splits, BN(n)+ReLU, bf16. Contiguous loads/stores.
// ---------------------------------------------------------------------------
__launch_bounds__(256)
__global__ void h0bn_kernel(const unsigned short* __restrict__ part,
                            const float* __restrict__ mean,
                            const float* __restrict__ var,
                            const float* __restrict__ gamma,
                            const float* __restrict__ beta,
                            unsigned short* __restrict__ h0T) {
  const int idx = (blockIdx.x * 256 + threadIdx.x) * 8;  // over 524288
  const int b = idx >> 15, f = (idx >> 9) & 63, n = idx & 511;
  const size_t off = ((size_t)f << 9) + n;
  u16x8 u0 = *(const u16x8*)(part + (((size_t)b) << 15) + off);
  u16x8 u1 = *(const u16x8*)(part + (((size_t)(16 + b)) << 15) + off);
  float4 mn0 = *(const float4*)(mean + n), mn1 = *(const float4*)(mean + n + 4);
  float4 vr0 = *(const float4*)(var + n), vr1 = *(const float4*)(var + n + 4);
  float4 gm0 = *(const float4*)(gamma + n), gm1 = *(const float4*)(gamma + n + 4);
  float4 bt0 = *(const float4*)(beta + n), bt1 = *(const float4*)(beta + n + 4);
  float mn[8] = {mn0.x, mn0.y, mn0.z, mn0.w, mn1.x, mn1.y, mn1.z, mn1.w};
  float vr[8] = {vr0.x, vr0.y, vr0.z, vr0.w, vr1.x, vr1.y, vr1.z, vr1.w};
  float gm[8] = {gm0.x, gm0.y, gm0.z, gm0.w, gm1.x, gm1.y, gm1.z, gm1.w};
  float bt[8] = {bt0.x, bt0.y, bt0.z, bt0.w, bt1.x, bt1.y, bt1.z, bt1.w};
  u16x8 o;
#pragma unroll
  for (int e = 0; e < 8; ++e) {
    float v = bf2f((unsigned short)u0[e]) + bf2f((unsigned short)u1[e]);
    float sc = rsqrtf(vr[e] + 1e-5f) * gm[e];
    float r = fmaf(v - mn[e], sc, bt[e]);
    o[e] = f2bf(fmaxf(r, 0.f));
  }
  *(u16x8*)(h0T + ((size_t)b << 15) + off) = o;
}

// ---------------------------------------------------------------------------
// fuse: h_next = relu(BN(h@W3 + b + sum_z P_z@W_z)), P_z = sum of S partials.
// Also emits summed P_z (bf16) for the next layer. Block: (b, 32 n), 256 thr.
// All global stores staged via LDS -> 64B-sector aligned.
// ---------------------------------------------------------------------------
struct FArgs {
  const unsigned short* hT;
  const unsigned short* Pp;
  int S;
  const float *W3, *W0, *W1, *W2;
  const float *bias, *mean, *var, *gamma, *beta;
  unsigned short* outT;
  unsigned short* P0o;
  unsigned short* P1o;
  unsigned short* P2o;
};

__launch_bounds__(256)
__global__ void fuse_kernel(FArgs f) {
  const int b = blockIdx.y, nb = blockIdx.x;  // 16 blocks of 32 n
  const int t = threadIdx.x;
  __shared__ float sums[4][64][17];
  __shared__ __align__(16) unsigned short outH[64][40];
  __shared__ __align__(16) unsigned short outP[3][64][40];
  const int mat = t >> 6, k = t & 63;
  const int fo = t & 63, gq = t >> 6;
  const bool wantP = (f.P0o != nullptr);
  const float* Ws[4] = {f.W3, f.W0, f.W1, f.W2};

  for (int sub = 0; sub < 2; ++sub) {
    const int n0 = nb * 32 + sub * 16;
    // stage: sums[mat][k][0..15] over n
    float v[16];
    if (mat == 0) {
      const unsigned short* sp = f.hT + ((size_t)b << 15) + ((size_t)k << 9) + n0;
      u16x8 lo = *(const u16x8*)sp, hi = *(const u16x8*)(sp + 8);
#pragma unroll
      for (int e = 0; e < 8; ++e) {
        v[e] = bf2f((unsigned short)lo[e]);
        v[8 + e] = bf2f((unsigned short)hi[e]);
      }
    } else {
#pragma unroll
      for (int e = 0; e < 16; ++e) v[e] = 0.f;
      const int z = mat - 1;
      for (int sp = 0; sp < f.S; ++sp) {
        const unsigned short* p =
            f.Pp + ((((size_t)z * f.S + sp) * 16 + b) << 15) + ((size_t)k << 9) + n0;
        u16x8 lo = *(const u16x8*)p, hi = *(const u16x8*)(p + 8);
#pragma unroll
        for (int e = 0; e < 8; ++e) {
          v[e] += bf2f((unsigned short)lo[e]);
          v[8 + e] += bf2f((unsigned short)hi[e]);
        }
      }
    }
#pragma unroll
    for (int e = 0; e < 16; ++e) sums[mat][k][e] = v[e];
    if (wantP && mat >= 1) {
      u16x8 pw0, pw1;
#pragma unroll
      for (int e = 0; e < 8; ++e) {
        pw0[e] = f2bf(v[e]);
        pw1[e] = f2bf(v[8 + e]);
      }
      *(u16x8*)&outP[mat - 1][k][sub * 16] = pw0;
      *(u16x8*)&outP[mat - 1][k][sub * 16 + 8] = pw1;
    }
    __syncthreads();
    // compute 4 n's per thread
    float acc[4] = {f.bias[fo], f.bias[fo], f.bias[fo], f.bias[fo]};
#pragma unroll
    for (int m2 = 0; m2 < 4; ++m2) {
      const float* __restrict__ W = Ws[m2];
#pragma unroll 8
      for (int k2 = 0; k2 < 64; ++k2) {
        float wv = W[k2 * 64 + fo];
#pragma unroll
        for (int i = 0; i < 4; ++i)
          acc[i] = fmaf(sums[m2][k2][gq * 4 + i], wv, acc[i]);
      }
    }
    ushort4 ov;
#pragma unroll
    for (int i = 0; i < 4; ++i) {
      int n = n0 + gq * 4 + i;
      float sc = rsqrtf(f.var[n] + 1e-5f) * f.gamma[n];
      float r = fmaf(acc[i] - f.mean[n], sc, f.beta[n]);
      ((unsigned short*)&ov)[i] = f2bf(fmaxf(r, 0.f));
    }
    *(ushort4*)&outH[fo][sub * 16 + gq * 4] = ov;
    __syncthreads();
  }

  // contiguous stores: [64 f][32 n] tiles
  const int fr = t >> 2, c4 = t & 3;  // 4 chunks of 8 n
  const size_t gb = ((size_t)b << 15) + ((size_t)fr << 9) + nb * 32 + c4 * 8;
  *(u16x8*)(f.outT + gb) = *(const u16x8*)&outH[fr][c4 * 8];
  if (wantP) {
    *(u16x8*)(f.P0o + gb) = *(const u16x8*)&outP[0][fr][c4 * 8];
    *(u16x8*)(f.P1o + gb) = *(const u16x8*)&outP[1][fr][c4 * 8];
    *(u16x8*)(f.P2o + gb) = *(const u16x8*)&outP[2][fr][c4 * 8];
  }
}

// ---------------------------------------------------------------------------
// head: sum over n -> BN+ReLU -> FC(512) -> softmax. 1 block / batch.
// ---------------------------------------------------------------------------
__launch_bounds__(256)
__global__ void head_T_kernel(const unsigned short* __restrict__ h3T,
                              const float* __restrict__ gmean,
                              const float* __restrict__ gvar,
                              const float* __restrict__ ggamma,
                              const float* __restrict__ gbeta,
                              const float* __restrict__ fc_w,
                              const float* __restrict__ fc_b,
                              float* __restrict__ out) {
  const int b = blockIdx.x;
  const int t = threadIdx.x;
  __shared__ float part[256];
  __shared__ float gh[64];
  __shared__ float red[256];

  const int f = t >> 2, q = t & 3;
  const unsigned short* hp = h3T + ((size_t)b << 15) + ((size_t)f << 9) + q * 128;
  float s = 0.f;
#pragma unroll
  for (int j = 0; j < 16; ++j) {
    u16x8 v = *(const u16x8*)(hp + j * 8);
#pragma unroll
    for (int e = 0; e < 8; ++e) s += bf2f((unsigned short)v[e]);
  }
  part[t] = s;
  __syncthreads();
  if (t < 64) {
    float sum = part[t * 4] + part[t * 4 + 1] + part[t * 4 + 2] + part[t * 4 + 3];
    float sc = rsqrtf(gvar[t] + 1e-5f) * ggamma[t];
    float v = fmaf(sum - gmean[t], sc, gbeta[t]);
    gh[t] = v > 0.f ? v : 0.f;
  }
  __syncthreads();

  float lg[2];
#pragma unroll
  for (int rep = 0; rep < 2; ++rep) {
    const int a = t + rep * 256;
    const float* __restrict__ wv = fc_w + (size_t)a * Fn;
    float acc = fc_b[a];
#pragma unroll 8
    for (int kk = 0; kk < 64; ++kk) acc = fmaf(gh[kk], wv[kk], acc);
    lg[rep] = acc;
  }
  red[t] = fmaxf(lg[0], lg[1]);
  __syncthreads();
  for (int off = 128; off > 0; off >>= 1) {
    if (t < off) red[t] = fmaxf(red[t], red[t + off]);
    __syncthreads();
  }
  const float mx = red[0];
  __syncthreads();
  const float e0 = __expf(lg[0] - mx), e1 = __expf(lg[1] - mx);
  red[t] = e0 + e1;
  __syncthreads();
  for (int off = 128; off > 0; off >>= 1) {
    if (t < off) red[t] += red[t + off];
    __syncthreads();
  }
  const float inv = 1.f / red[0];
  out[(size_t)b * Aout + t] = e0 * inv;
  out[(size_t)b * Aout + t + 256] = e1 * inv;
}

// ---------------------------------------------------------------------------
extern "C" void kernel_launch(void* const* d_in, const int* in_sizes, int n_in,
                              void* d_out, int out_size, void* d_ws,
                              size_t ws_size, hipStream_t stream) {
  (void)in_sizes; (void)n_in; (void)out_size; (void)ws_size;
  const float* hs_init = (const float*)d_in[0];
  const float* adjs0 = (const float*)d_in[1];
  const float* adjs1 = (const float*)d_in[2];
  const float* adjs2 = (const float*)d_in[3];
  const float* W_init = (const float*)d_in[4];
  const float* W0 = (const float*)d_in[5];
  const float* W1 = (const float*)d_in[6];
  const float* W2 = (const float*)d_in[7];
  const float* W3 = (const float*)d_in[8];
  const float* bvec = (const float*)d_in[9];
  const float* fc1_w = (const float*)d_in[10];
  const float* fc1_b = (const float*)d_in[11];
  const float* bn_init_mean = (const float*)d_in[12];
  const float* bn_init_var = (const float*)d_in[13];
  const float* bn_init_gamma = (const float*)d_in[14];
  const float* bn_init_beta = (const float*)d_in[15];
  const float* bn_layer_mean = (const float*)d_in[16];
  const float* bn_layer_var = (const float*)d_in[17];
  const float* bn_layer_gamma = (const float*)d_in[18];
  const float* bn_layer_beta = (const float*)d_in[19];
  const float* bn_graph_mean = (const float*)d_in[20];
  const float* bn_graph_var = (const float*)d_in[21];
  const float* bn_graph_gamma = (const float*)d_in[22];
  const float* bn_graph_beta = (const float*)d_in[23];

  const size_t ADJ = (size_t)Bn * Nn * Nn;  // 4,194,304
  const size_t NF = (size_t)Bn * Fn * Nn;   // 524,288

  unsigned short* wsu = (unsigned short*)d_ws;
  unsigned short* adjsum = wsu;
  unsigned short* WiT = adjsum + ADJ;
  unsigned short* h0T = WiT + 32768;
  unsigned short* h1T = h0T + NF;
  unsigned short* h2T = h1T + NF;
  unsigned short* h3T = h2T + NF;
  unsigned short* P0 = h3T + NF;
  unsigned short* P1 = P0 + NF;
  unsigned short* P2 = P1 + NF;
  unsigned short* part = P2 + NF;  // 3*4*16*32768 = 6,291,456 elems max

  // 1) prep: adjs sum -> bf16; W_init^T -> bf16
  prep_kernel<<<dim3(4096 + 128), dim3(256), 0, stream>>>(
      (const float4*)adjs0, (const float4*)adjs1, (const float4*)adjs2,
      (ushort4*)adjsum, W_init, WiT);

  // 2) h0 partials = hs_init(fp32) @ WiT, split K into 2
  {
    GArgs a = {};
    a.A0f[0] = hs_init;
    a.X0[0] = WiT;
    a.O = part;
    a.x0_bs = 0;
    a.nz = 1; a.ns0 = 2; a.ns = 2;
    gemm_split_kernel<<<dim3(8, Bn, 2), dim3(256), 0, stream>>>(a);
  }
  // 3) h0 = relu(BN_init(sum partials))
  h0bn_kernel<<<dim3(256), dim3(256), 0, stream>>>(
      part, bn_init_mean, bn_init_var, bn_init_gamma, bn_init_beta, h0T);

  // 4) L0 partials: adjs_z(fp32) @ h0
  {
    GArgs a = {};
    a.A0f[0] = adjs0; a.A0f[1] = adjs1; a.A0f[2] = adjs2;
    a.X0[0] = h0T; a.X0[1] = h0T; a.X0[2] = h0T;
    a.O = part;
    a.x0_bs = 32768;
    a.nz = 3; a.ns0 = 2; a.ns = 2;
    gemm_split_kernel<<<dim3(8, Bn, 2), dim3(256), 0, stream>>>(a);
  }
  // 5) fuse L0 -> h1T, P_k[0]
  {
    FArgs fa = {};
    fa.hT = h0T; fa.Pp = part; fa.S = 2;
    fa.W3 = W3; fa.W0 = W0; fa.W1 = W1; fa.W2 = W2;
    fa.bias = bvec; fa.mean = bn_layer_mean; fa.var = bn_layer_var;
    fa.gamma = bn_layer_gamma; fa.beta = bn_layer_beta;
    fa.outT = h1T; fa.P0o = P0; fa.P1o = P1; fa.P2o = P2;
    fuse_kernel<<<dim3(16, Bn), dim3(256), 0, stream>>>(fa);
  }

  // 6) L1 partials: adjs_z @ h1 (splits 0-1) + adjsum @ P_k[0] (splits 2-3)
  {
    GArgs a = {};
    a.A0f[0] = adjs0; a.A0f[1] = adjs1; a.A0f[2] = adjs2;
    a.A1 = adjsum;
    a.X0[0] = h1T; a.X0[1] = h1T; a.X0[2] = h1T;
    a.X1[0] = P0; a.X1[1] = P1; a.X1[2] = P2;
    a.O = part;
    a.x0_bs = 32768;
    a.nz = 3; a.ns0 = 2; a.ns = 4;
    gemm_split_kernel<<<dim3(8, Bn, 4), dim3(256), 0, stream>>>(a);
  }
  // 7) fuse L1 -> h2T, P_k[1]
  {
    FArgs fa = {};
    fa.hT = h1T; fa.Pp = part; fa.S = 4;
    fa.W3 = W3 + 4096; fa.W0 = W0 + 4096; fa.W1 = W1 + 4096; fa.W2 = W2 + 4096;
    fa.bias = bvec + 64; fa.mean = bn_layer_mean + 512; fa.var = bn_layer_var + 512;
    fa.gamma = bn_layer_gamma + 512; fa.beta = bn_layer_beta + 512;
    fa.outT = h2T; fa.P0o = P0; fa.P1o = P1; fa.P2o = P2;
    fuse_kernel<<<dim3(16, Bn), dim3(256), 0, stream>>>(fa);
  }

  // 8) L2 partials
  {
    GArgs a = {};
    a.A0f[0] = adjs0; a.A0f[1] = adjs1; a.A0f[2] = adjs2;
    a.A1 = adjsum;
    a.X0[0] = h2T; a.X0[1] = h2T; a.X0[2] = h2T;
    a.X1[0] = P0; a.X1[1] = P1; a.X1[2] = P2;
    a.O = part;
    a.x0_bs = 32768;
    a.nz = 3; a.ns0 = 2; a.ns = 4;
    gemm_split_kernel<<<dim3(8, Bn, 4), dim3(256), 0, stream>>>(a);
  }
  // 9) fuse L2 -> h3T (no P outputs)
  {
    FArgs fa = {};
    fa.hT = h2T; fa.Pp = part; fa.S = 4;
    fa.W3 = W3 + 8192; fa.W0 = W0 + 8192; fa.W1 = W1 + 8192; fa.W2 = W2 + 8192;
    fa.bias = bvec + 128; fa.mean = bn_layer_mean + 1024; fa.var = bn_layer_var + 1024;
    fa.gamma = bn_layer_gamma + 1024; fa.beta = bn_layer_beta + 1024;
    fa.outT = h3T; fa.P0o = nullptr; fa.P1o = nullptr; fa.P2o = nullptr;
    fuse_kernel<<<dim3(16, Bn), dim3(256), 0, stream>>>(fa);
  }

  // 10) head
  head_T_kernel<<<dim3(Bn), dim3(256), 0, stream>>>(
      h3T, bn_graph_mean, bn_graph_var, bn_graph_gamma, bn_graph_beta, fc1_w,
      fc1_b, (float*)d_out);
}

// Round 5
// 182.695 us; speedup vs baseline: 1.0711x; 1.0427x over previous
//
#include <hip/hip_runtime.h>

typedef __attribute__((ext_vector_type(8))) short bf16x8;
typedef __attribute__((ext_vector_type(4))) float f32x4;
typedef __attribute__((ext_vector_type(8))) unsigned short u16x8;

constexpr int Bn = 16;
constexpr int Nn = 512;
constexpr int Fn = 64;
constexpr int Aout = 512;

static __device__ __forceinline__ unsigned short f2bf(float f) {
  union { float f; unsigned int u; } v; v.f = f;
  unsigned int r = v.u + 0x7fffu + ((v.u >> 16) & 1u);
  return (unsigned short)(r >> 16);
}
static __device__ __forceinline__ float bf2f(unsigned short u) {
  union { unsigned int u; float f; } v; v.u = ((unsigned int)u) << 16;
  return v.f;
}

// ---------------------------------------------------------------------------
// prep: [0,4096) adjs->bf16 x3 + bf16 sum; [4096,8192) hs_init->bf16;
//       [8192,8320) W_init -> W_init^T bf16.
// ---------------------------------------------------------------------------
__launch_bounds__(256)
__global__ void prep_kernel(const float4* __restrict__ a0,
                            const float4* __restrict__ a1,
                            const float4* __restrict__ a2,
                            const float4* __restrict__ hs,
                            ushort4* __restrict__ o0,
                            ushort4* __restrict__ o1,
                            ushort4* __restrict__ o2,
                            ushort4* __restrict__ osum,
                            ushort4* __restrict__ ohs,
                            const float* __restrict__ Wi,
                            unsigned short* __restrict__ WiT) {
  const int blk = blockIdx.x;
  if (blk < 4096) {
    size_t i = (size_t)blk * 256 + threadIdx.x;
    float4 x = a0[i], y = a1[i], z = a2[i];
    ushort4 p;
    p.x = f2bf(x.x); p.y = f2bf(x.y); p.z = f2bf(x.z); p.w = f2bf(x.w);
    o0[i] = p;
    p.x = f2bf(y.x); p.y = f2bf(y.y); p.z = f2bf(y.z); p.w = f2bf(y.w);
    o1[i] = p;
    p.x = f2bf(z.x); p.y = f2bf(z.y); p.z = f2bf(z.z); p.w = f2bf(z.w);
    o2[i] = p;
    p.x = f2bf(x.x + y.x + z.x); p.y = f2bf(x.y + y.y + z.y);
    p.z = f2bf(x.z + y.z + z.z); p.w = f2bf(x.w + y.w + z.w);
    osum[i] = p;
  } else if (blk < 8192) {
    size_t i = (size_t)(blk - 4096) * 256 + threadIdx.x;
    float4 x = hs[i];
    ushort4 p;
    p.x = f2bf(x.x); p.y = f2bf(x.y); p.z = f2bf(x.z); p.w = f2bf(x.w);
    ohs[i] = p;
  } else {
    int o = (blk - 8192) * 256 + threadIdx.x;  // 32768 = 64f x 512k
    int f = o >> 9, k = o & 511;
    WiT[o] = f2bf(Wi[k * Fn + f]);
  }
}

// ---------------------------------------------------------------------------
// Chunked MFMA GEMM. One block = one (slot, b, 64-row tile); slot encodes
// {A matrix, X matrix, K-chunk base}; K chunk = 256. All bf16.
// Output partial bf16 [slot][b][64f][512n] via LDS-transposed contiguous
// stores. Low per-thread footprint; latency hidden by occupancy
// (4+ blocks/CU via __launch_bounds__(256,4)).
// ---------------------------------------------------------------------------
struct Slot {
  const unsigned short* A;  // [16][512][512] row-major
  const unsigned short* X;  // [*(b)][64][512] f-major
  long long xbs;            // X batch stride (0 = shared)
  int kbase;
};
struct GArgs {
  Slot s[12];
  unsigned short* O;
};

__launch_bounds__(256, 4)
__global__ void gemm_chunk_kernel(GArgs g) {
  const int slot = blockIdx.z, b = blockIdx.y;
  const int R0 = blockIdx.x * 64;
  const int tid = threadIdx.x;
  const int w = tid >> 6, l = tid & 63;
  const int lr = l & 15, q = l >> 4;
  const Slot sl = g.s[slot];

  const unsigned short* A = sl.A + ((size_t)b << 18) +
                            ((size_t)(R0 + w * 16 + lr) << 9) + sl.kbase + q * 8;
  const unsigned short* X = sl.X + (size_t)b * sl.xbs + ((size_t)lr << 9) +
                            sl.kbase + q * 8;

  f32x4 acc[4] = {{0.f, 0.f, 0.f, 0.f},
                  {0.f, 0.f, 0.f, 0.f},
                  {0.f, 0.f, 0.f, 0.f},
                  {0.f, 0.f, 0.f, 0.f}};

#pragma unroll 2
  for (int k = 0; k < 8; ++k) {
    bf16x8 af = *(const bf16x8*)(A + k * 32);
#pragma unroll
    for (int c = 0; c < 4; ++c) {
      bf16x8 xf = *(const bf16x8*)(X + c * 8192 + k * 32);
      acc[c] = __builtin_amdgcn_mfma_f32_16x16x32_bf16(af, xf, acc[c], 0, 0, 0);
    }
  }

  // LDS transpose -> contiguous [f][n] partial stores
  __shared__ __align__(16) unsigned short outLDS[64][72];
#pragma unroll
  for (int c = 0; c < 4; ++c) {
    ushort4 wv;
#pragma unroll
    for (int i = 0; i < 4; ++i) ((unsigned short*)&wv)[i] = f2bf(acc[c][i]);
    *(ushort4*)&outLDS[c * 16 + lr][w * 16 + q * 4] = wv;
  }
  __syncthreads();
  {
    const int fr = tid >> 2, c4 = tid & 3;
    unsigned short* O = g.O + (((size_t)slot * 16 + b) << 15) +
                        ((size_t)fr << 9) + R0 + c4 * 16;
    u16x8 v0 = *(const u16x8*)&outLDS[fr][c4 * 16];
    u16x8 v1 = *(const u16x8*)&outLDS[fr][c4 * 16 + 8];
    *(u16x8*)O = v0;
    *(u16x8*)(O + 8) = v1;
  }
}

// ---------------------------------------------------------------------------
// h0 epilogue: sum 2 split partials, BN(n)+ReLU, bf16.
// ---------------------------------------------------------------------------
__launch_bounds__(256)
__global__ void h0bn_kernel(const unsigned short* __restrict__ part,
                            const float* __restrict__ mean,
                            const float* __restrict__ var,
                            const float* __restrict__ gamma,
                            const float* __restrict__ beta,
                            unsigned short* __restrict__ h0T) {
  const int idx = (blockIdx.x * 256 + threadIdx.x) * 8;  // over 524288
  const int b = idx >> 15, n = idx & 511;
  const size_t off = (size_t)(idx & 32767);
  u16x8 u0 = *(const u16x8*)(part + (((size_t)b) << 15) + off);
  u16x8 u1 = *(const u16x8*)(part + (((size_t)(16 + b)) << 15) + off);
  u16x8 o;
#pragma unroll
  for (int e = 0; e < 8; ++e) {
    float v = bf2f((unsigned short)u0[e]) + bf2f((unsigned short)u1[e]);
    float sc = rsqrtf(var[n + e] + 1e-5f) * gamma[n + e];
    float r = fmaf(v - mean[n + e], sc, beta[n + e]);
    o[e] = f2bf(fmaxf(r, 0.f));
  }
  *(u16x8*)(h0T + ((size_t)b << 15) + off) = o;
}

// ---------------------------------------------------------------------------
// fuse: h_next = relu(BN(h@W3 + b + sum_z P_z@W_z)), P_z = sum of S partials.
// Optionally emits summed P_z (bf16). Block: (b, 32 n), 256 thr.
// ---------------------------------------------------------------------------
struct FArgs {
  const unsigned short* hT;
  const unsigned short* Pp;
  int S;
  const float *W3, *W0, *W1, *W2;
  const float *bias, *mean, *var, *gamma, *beta;
  unsigned short* outT;
  unsigned short* P0o;
  unsigned short* P1o;
  unsigned short* P2o;
};

__launch_bounds__(256)
__global__ void fuse_kernel(FArgs f) {
  const int b = blockIdx.y, nb = blockIdx.x;  // 16 blocks of 32 n
  const int t = threadIdx.x;
  __shared__ float sums[4][64][17];
  __shared__ __align__(16) unsigned short outH[64][40];
  __shared__ __align__(16) unsigned short outP[3][64][40];
  const int mat = t >> 6, k = t & 63;
  const int fo = t & 63, gq = t >> 6;
  const bool wantP = (f.P0o != nullptr);
  const float* Ws[4] = {f.W3, f.W0, f.W1, f.W2};

  for (int sub = 0; sub < 2; ++sub) {
    const int n0 = nb * 32 + sub * 16;
    float v[16];
    if (mat == 0) {
      const unsigned short* sp = f.hT + ((size_t)b << 15) + ((size_t)k << 9) + n0;
      u16x8 lo = *(const u16x8*)sp, hi = *(const u16x8*)(sp + 8);
#pragma unroll
      for (int e = 0; e < 8; ++e) {
        v[e] = bf2f((unsigned short)lo[e]);
        v[8 + e] = bf2f((unsigned short)hi[e]);
      }
    } else {
#pragma unroll
      for (int e = 0; e < 16; ++e) v[e] = 0.f;
      const int z = mat - 1;
      for (int sp = 0; sp < f.S; ++sp) {
        const unsigned short* p =
            f.Pp + ((((size_t)z * f.S + sp) * 16 + b) << 15) + ((size_t)k << 9) + n0;
        u16x8 lo = *(const u16x8*)p, hi = *(const u16x8*)(p + 8);
#pragma unroll
        for (int e = 0; e < 8; ++e) {
          v[e] += bf2f((unsigned short)lo[e]);
          v[8 + e] += bf2f((unsigned short)hi[e]);
        }
      }
    }
#pragma unroll
    for (int e = 0; e < 16; ++e) sums[mat][k][e] = v[e];
    if (wantP && mat >= 1) {
      u16x8 pw0, pw1;
#pragma unroll
      for (int e = 0; e < 8; ++e) {
        pw0[e] = f2bf(v[e]);
        pw1[e] = f2bf(v[8 + e]);
      }
      *(u16x8*)&outP[mat - 1][k][sub * 16] = pw0;
      *(u16x8*)&outP[mat - 1][k][sub * 16 + 8] = pw1;
    }
    __syncthreads();
    float acc[4] = {f.bias[fo], f.bias[fo], f.bias[fo], f.bias[fo]};
#pragma unroll
    for (int m2 = 0; m2 < 4; ++m2) {
      const float* __restrict__ W = Ws[m2];
#pragma unroll 8
      for (int k2 = 0; k2 < 64; ++k2) {
        float wv = W[k2 * 64 + fo];
#pragma unroll
        for (int i = 0; i < 4; ++i)
          acc[i] = fmaf(sums[m2][k2][gq * 4 + i], wv, acc[i]);
      }
    }
    ushort4 ov;
#pragma unroll
    for (int i = 0; i < 4; ++i) {
      int n = n0 + gq * 4 + i;
      float sc = rsqrtf(f.var[n] + 1e-5f) * f.gamma[n];
      float r = fmaf(acc[i] - f.mean[n], sc, f.beta[n]);
      ((unsigned short*)&ov)[i] = f2bf(fmaxf(r, 0.f));
    }
    *(ushort4*)&outH[fo][sub * 16 + gq * 4] = ov;
    __syncthreads();
  }

  const int fr = t >> 2, c4 = t & 3;
  const size_t gb = ((size_t)b << 15) + ((size_t)fr << 9) + nb * 32 + c4 * 8;
  *(u16x8*)(f.outT + gb) = *(const u16x8*)&outH[fr][c4 * 8];
  if (wantP) {
    *(u16x8*)(f.P0o + gb) = *(const u16x8*)&outP[0][fr][c4 * 8];
    *(u16x8*)(f.P1o + gb) = *(const u16x8*)&outP[1][fr][c4 * 8];
    *(u16x8*)(f.P2o + gb) = *(const u16x8*)&outP[2][fr][c4 * 8];
  }
}

// ---------------------------------------------------------------------------
// head: sum over n -> BN+ReLU -> FC(512) -> softmax. 1 block / batch.
// ---------------------------------------------------------------------------
__launch_bounds__(256)
__global__ void head_T_kernel(const unsigned short* __restrict__ h3T,
                              const float* __restrict__ gmean,
                              const float* __restrict__ gvar,
                              const float* __restrict__ ggamma,
                              const float* __restrict__ gbeta,
                              const float* __restrict__ fc_w,
                              const float* __restrict__ fc_b,
                              float* __restrict__ out) {
  const int b = blockIdx.x;
  const int t = threadIdx.x;
  __shared__ float part[256];
  __shared__ float gh[64];
  __shared__ float red[256];

  const int f = t >> 2, q = t & 3;
  const unsigned short* hp = h3T + ((size_t)b << 15) + ((size_t)f << 9) + q * 128;
  float s = 0.f;
#pragma unroll
  for (int j = 0; j < 16; ++j) {
    u16x8 v = *(const u16x8*)(hp + j * 8);
#pragma unroll
    for (int e = 0; e < 8; ++e) s += bf2f((unsigned short)v[e]);
  }
  part[t] = s;
  __syncthreads();
  if (t < 64) {
    float sum = part[t * 4] + part[t * 4 + 1] + part[t * 4 + 2] + part[t * 4 + 3];
    float sc = rsqrtf(gvar[t] + 1e-5f) * ggamma[t];
    float v = fmaf(sum - gmean[t], sc, gbeta[t]);
    gh[t] = v > 0.f ? v : 0.f;
  }
  __syncthreads();

  float lg[2];
#pragma unroll
  for (int rep = 0; rep < 2; ++rep) {
    const int a = t + rep * 256;
    const float* __restrict__ wv = fc_w + (size_t)a * Fn;
    float acc = fc_b[a];
#pragma unroll 8
    for (int kk = 0; kk < 64; ++kk) acc = fmaf(gh[kk], wv[kk], acc);
    lg[rep] = acc;
  }
  red[t] = fmaxf(lg[0], lg[1]);
  __syncthreads();
  for (int off = 128; off > 0; off >>= 1) {
    if (t < off) red[t] = fmaxf(red[t], red[t + off]);
    __syncthreads();
  }
  const float mx = red[0];
  __syncthreads();
  const float e0 = __expf(lg[0] - mx), e1 = __expf(lg[1] - mx);
  red[t] = e0 + e1;
  __syncthreads();
  for (int off = 128; off > 0; off >>= 1) {
    if (t < off) red[t] += red[t + off];
    __syncthreads();
  }
  const float inv = 1.f / red[0];
  out[(size_t)b * Aout + t] = e0 * inv;
  out[(size_t)b * Aout + t + 256] = e1 * inv;
}

// ---------------------------------------------------------------------------
extern "C" void kernel_launch(void* const* d_in, const int* in_sizes, int n_in,
                              void* d_out, int out_size, void* d_ws,
                              size_t ws_size, hipStream_t stream) {
  (void)in_sizes; (void)n_in; (void)out_size; (void)ws_size;
  const float* hs_init = (const float*)d_in[0];
  const float* adjs0 = (const float*)d_in[1];
  const float* adjs1 = (const float*)d_in[2];
  const float* adjs2 = (const float*)d_in[3];
  const float* W_init = (const float*)d_in[4];
  const float* W0 = (const float*)d_in[5];
  const float* W1 = (const float*)d_in[6];
  const float* W2 = (const float*)d_in[7];
  const float* W3 = (const float*)d_in[8];
  const float* bvec = (const float*)d_in[9];
  const float* fc1_w = (const float*)d_in[10];
  const float* fc1_b = (const float*)d_in[11];
  const float* bn_init_mean = (const float*)d_in[12];
  const float* bn_init_var = (const float*)d_in[13];
  const float* bn_init_gamma = (const float*)d_in[14];
  const float* bn_init_beta = (const float*)d_in[15];
  const float* bn_layer_mean = (const float*)d_in[16];
  const float* bn_layer_var = (const float*)d_in[17];
  const float* bn_layer_gamma = (const float*)d_in[18];
  const float* bn_layer_beta = (const float*)d_in[19];
  const float* bn_graph_mean = (const float*)d_in[20];
  const float* bn_graph_var = (const float*)d_in[21];
  const float* bn_graph_gamma = (const float*)d_in[22];
  const float* bn_graph_beta = (const float*)d_in[23];

  const size_t ADJ = (size_t)Bn * Nn * Nn;  // 4,194,304
  const size_t NF = (size_t)Bn * Fn * Nn;   // 524,288

  unsigned short* wsu = (unsigned short*)d_ws;
  unsigned short* adjsum = wsu;
  unsigned short* a0b = adjsum + ADJ;
  unsigned short* a1b = a0b + ADJ;
  unsigned short* a2b = a1b + ADJ;
  unsigned short* hsb = a2b + ADJ;
  unsigned short* WiT = hsb + ADJ;        // 32768
  unsigned short* h0T = WiT + 32768;
  unsigned short* h1T = h0T + NF;
  unsigned short* h2T = h1T + NF;
  unsigned short* h3T = h2T + NF;
  unsigned short* P0 = h3T + NF;
  unsigned short* P1 = P0 + NF;
  unsigned short* P2 = P1 + NF;
  unsigned short* part = P2 + NF;  // up to 12*16*32768 = 6,291,456 elems

  // 1) prep
  prep_kernel<<<dim3(8192 + 128), dim3(256), 0, stream>>>(
      (const float4*)adjs0, (const float4*)adjs1, (const float4*)adjs2,
      (const float4*)hs_init, (ushort4*)a0b, (ushort4*)a1b, (ushort4*)a2b,
      (ushort4*)adjsum, (ushort4*)hsb, W_init, WiT);

  // 2) h0 partials: hs @ WiT, 2 K-chunks
  {
    GArgs a = {};
    for (int c = 0; c < 2; ++c) a.s[c] = {hsb, WiT, 0, c * 256};
    a.O = part;
    gemm_chunk_kernel<<<dim3(8, Bn, 2), dim3(256), 0, stream>>>(a);
  }
  // 3) h0 = relu(BN_init(sum))
  h0bn_kernel<<<dim3(256), dim3(256), 0, stream>>>(
      part, bn_init_mean, bn_init_var, bn_init_gamma, bn_init_beta, h0T);

  const unsigned short* ab[3] = {a0b, a1b, a2b};

  // 4) L0: slots z*2+c = a_z @ h0 chunk c
  {
    GArgs a = {};
    for (int z = 0; z < 3; ++z)
      for (int c = 0; c < 2; ++c)
        a.s[z * 2 + c] = {ab[z], h0T, 32768, c * 256};
    a.O = part;
    gemm_chunk_kernel<<<dim3(8, Bn, 6), dim3(256), 0, stream>>>(a);
  }
  // 5) fuse L0 (S=2) -> h1, P_z
  {
    FArgs fa = {};
    fa.hT = h0T; fa.Pp = part; fa.S = 2;
    fa.W3 = W3; fa.W0 = W0; fa.W1 = W1; fa.W2 = W2;
    fa.bias = bvec; fa.mean = bn_layer_mean; fa.var = bn_layer_var;
    fa.gamma = bn_layer_gamma; fa.beta = bn_layer_beta;
    fa.outT = h1T; fa.P0o = P0; fa.P1o = P1; fa.P2o = P2;
    fuse_kernel<<<dim3(16, Bn), dim3(256), 0, stream>>>(fa);
  }

  const unsigned short* Ps[3] = {P0, P1, P2};

  // 6) L1: slots z*4+{0,1} = a_z @ h1; z*4+{2,3} = adjsum @ P_z
  {
    GArgs a = {};
    for (int z = 0; z < 3; ++z) {
      for (int c = 0; c < 2; ++c) {
        a.s[z * 4 + c] = {ab[z], h1T, 32768, c * 256};
        a.s[z * 4 + 2 + c] = {adjsum, Ps[z], 32768, c * 256};
      }
    }
    a.O = part;
    gemm_chunk_kernel<<<dim3(8, Bn, 12), dim3(256), 0, stream>>>(a);
  }
  // 7) fuse L1 (S=4) -> h2, P_z
  {
    FArgs fa = {};
    fa.hT = h1T; fa.Pp = part; fa.S = 4;
    fa.W3 = W3 + 4096; fa.W0 = W0 + 4096; fa.W1 = W1 + 4096; fa.W2 = W2 + 4096;
    fa.bias = bvec + 64; fa.mean = bn_layer_mean + 512;
    fa.var = bn_layer_var + 512; fa.gamma = bn_layer_gamma + 512;
    fa.beta = bn_layer_beta + 512;
    fa.outT = h2T; fa.P0o = P0; fa.P1o = P1; fa.P2o = P2;
    fuse_kernel<<<dim3(16, Bn), dim3(256), 0, stream>>>(fa);
  }

  // 8) L2
  {
    GArgs a = {};
    for (int z = 0; z < 3; ++z) {
      for (int c = 0; c < 2; ++c) {
        a.s[z * 4 + c] = {ab[z], h2T, 32768, c * 256};
        a.s[z * 4 + 2 + c] = {adjsum, Ps[z], 32768, c * 256};
      }
    }
    a.O = part;
    gemm_chunk_kernel<<<dim3(8, Bn, 12), dim3(256), 0, stream>>>(a);
  }
  // 9) fuse L2 (S=4) -> h3 only
  {
    FArgs fa = {};
    fa.hT = h2T; fa.Pp = part; fa.S = 4;
    fa.W3 = W3 + 8192; fa.W0 = W0 + 8192; fa.W1 = W1 + 8192; fa.W2 = W2 + 8192;
    fa.bias = bvec + 128; fa.mean = bn_layer_mean + 1024;
    fa.var = bn_layer_var + 1024; fa.gamma = bn_layer_gamma + 1024;
    fa.beta = bn_layer_beta + 1024;
    fa.outT = h3T; fa.P0o = nullptr; fa.P1o = nullptr; fa.P2o = nullptr;
    fuse_kernel<<<dim3(16, Bn), dim3(256), 0, stream>>>(fa);
  }

  // 10) head
  head_T_kernel<<<dim3(Bn), dim3(256), 0, stream>>>(
      h3T, bn_graph_mean, bn_graph_var, bn_graph_gamma, bn_graph_beta, fc1_w,
      fc1_b, (float*)d_out);
}